// Round 3
// baseline (315.357 us; speedup 1.0000x reference)
//
#include <hip/hip_runtime.h>
#include <stdint.h>

#define NROI 2000
#define MPAD 2048
#define KP   12544   // 256*49
#define N1   1024
#define NCLS 81
#define NBOX 324
#define N3   405
#define N3P  448
#define BN_EPS 0.001f
#define KSPLIT 8

typedef __attribute__((ext_vector_type(8))) short bf16x8;
typedef __attribute__((ext_vector_type(4))) float f32x4;
typedef __attribute__((ext_vector_type(8))) unsigned short u16x8;

__device__ inline unsigned short f2bf(float f) {
  union { float f; unsigned u; } v; v.f = f;
  unsigned r = v.u + 0x7fffu + ((v.u >> 16) & 1u);
  return (unsigned short)(r >> 16);
}

__device__ inline float bf2f(unsigned short h) {
  union { unsigned u; float f; } v; v.u = (unsigned)h << 16; return v.f;
}

__device__ inline void gld16(const unsigned short* g, unsigned short* l) {
  __builtin_amdgcn_global_load_lds(
      (const __attribute__((address_space(1))) void*)g,
      (__attribute__((address_space(3))) void*)l, 16, 0, 0);
}

// K-slice table: 4 slices of 1536 + 4 of 1600 (all BK=64, no tail)
__device__ __forceinline__ void kslice(int kz, int& off, int& len) {
  if (kz < 4) { off = kz * 1536; len = 1536; }
  else        { off = 6144 + (kz - 4) * 1600; len = 1600; }
}

// =================== front_t: fmap transpose only ==========================
// [256][HW] f32 -> [HW][256] bf16, in-register, no LDS. 1360 blocks.
__global__ __launch_bounds__(256) void front_t(
    const float* __restrict__ p2, const float* __restrict__ p3,
    const float* __restrict__ p4, const float* __restrict__ p5,
    unsigned short* __restrict__ f2t, unsigned short* __restrict__ f3t,
    unsigned short* __restrict__ f4t, unsigned short* __restrict__ f5t) {
  int bb2 = blockIdx.x;
  int t = threadIdx.x;
  const float* src;
  unsigned short* dst;
  int HW;
  if (bb2 < 1024)      { src = p2; dst = f2t; HW = 65536; }
  else if (bb2 < 1280) { bb2 -= 1024; src = p3; dst = f3t; HW = 16384; }
  else if (bb2 < 1344) { bb2 -= 1280; src = p4; dst = f4t; HW = 4096; }
  else                 { bb2 -= 1344; src = p5; dst = f5t; HW = 1024; }
  int p0 = bb2 * 64;
  int lane = t & 63, w = t >> 6;
  int pq = (lane & 15) * 4;       // pixel quad within tile
  int cg = (lane >> 4) * 8;       // channel sub-block
#pragma unroll
  for (int it = 0; it < 2; ++it) {
    int c = w * 64 + it * 32 + cg;
    const float* sp = src + (size_t)c * HW + p0 + pq;
    float4 v[8];
#pragma unroll
    for (int k = 0; k < 8; ++k)
      v[k] = *(const float4*)(sp + (size_t)k * HW);
    unsigned short* dp = dst + (size_t)(p0 + pq) * 256 + c;
    u16x8 o0, o1, o2, o3;
#pragma unroll
    for (int k = 0; k < 8; ++k) {
      o0[k] = f2bf(v[k].x);
      o1[k] = f2bf(v[k].y);
      o2[k] = f2bf(v[k].z);
      o3[k] = f2bf(v[k].w);
    }
    *(u16x8*)(dp)       = o0;
    *(u16x8*)(dp + 256) = o1;
    *(u16x8*)(dp + 512) = o2;
    *(u16x8*)(dp + 768) = o3;
  }
}

// =================== roi_prep: ROI Align + weight prep (merged grid) =======
// blocks [0,2048): ROI Align gather from [HW][256] bf16 maps
// blocks [2048,4096): repack conv1_w half-rows -> w1p [o][hw*256+c] bf16
// blocks [4096,5120): cvt conv2_w -> bf16 (float4)
// blocks [5120,5568): pack logits_w+bbox_w -> w3b
// block 5568: BN folding + bias concat
// Weight outputs are consumed only by later kernels (stream-ordered).
__global__ __launch_bounds__(256) void roi_prep(
    const unsigned short* __restrict__ f2t, const unsigned short* __restrict__ f3t,
    const unsigned short* __restrict__ f4t, const unsigned short* __restrict__ f5t,
    const float* __restrict__ rois, unsigned short* __restrict__ pooled,
    const float* __restrict__ c1w, const float* __restrict__ c2w,
    const float* __restrict__ lw, const float* __restrict__ bw,
    const float* c1b, const float* g1, const float* b1, const float* m1, const float* v1,
    const float* c2b, const float* g2, const float* b2, const float* m2, const float* v2,
    const float* lb, const float* bb,
    unsigned short* __restrict__ w1p, unsigned short* __restrict__ w2b,
    unsigned short* __restrict__ w3b,
    float* s1, float* t1, float* s2, float* t2, float* b3) {
  __shared__ unsigned short srep[6272];  // 12544 B, repack branch only
  int b = blockIdx.x;
  int t = threadIdx.x;
  if (b < 2048) {
    int n = b;
    int lane = t & 63, w = t >> 6;
    int c0 = lane * 4;
    unsigned short* out = pooled + (size_t)n * KP;
    if (n >= NROI) {
      for (int p = w; p < 49; p += 4)
        *(ushort4*)(out + p * 256 + c0) = make_ushort4(0, 0, 0, 0);
      return;
    }
    float x1 = rois[n * 4 + 0], y1 = rois[n * 4 + 1];
    float x2 = rois[n * 4 + 2], y2 = rois[n * 4 + 3];
    float area = (y2 - y1) * (x2 - x1);
    float lvl_f = rintf(log2f(sqrtf(area) / 224.0f)) + 4.0f;
    lvl_f = fminf(fmaxf(lvl_f, 2.0f), 5.0f);
    int lvl = (int)lvl_f;
    const unsigned short* f;
    int H;
    if (lvl == 2)      { f = f2t; H = 256; }
    else if (lvl == 3) { f = f3t; H = 128; }
    else if (lvl == 4) { f = f4t; H = 64;  }
    else               { f = f5t; H = 32;  }
    int W = H;
    const float inv = 1.0f / 1024.0f;
    float yn1 = y1 * inv, xn1 = x1 * inv, yn2 = y2 * inv, xn2 = x2 * inv;
    float hs = (yn2 - yn1) * (H - 1);
    float ws = (xn2 - xn1) * (W - 1);
    float yb = yn1 * (H - 1);
    float xb = xn1 * (W - 1);

    for (int p = w; p < 49; p += 4) {
      int py = p / 7, px = p - py * 7;
      float ysv = yb + ((float)py / 6.0f) * hs;
      float xsv = xb + ((float)px / 6.0f) * ws;
      float y0f = floorf(ysv), x0f = floorf(xsv);
      float ly = ysv - y0f, lx = xsv - x0f;
      int y0 = min(max((int)y0f, 0), H - 1);
      int y1i = min(y0 + 1, H - 1);
      int x0 = min(max((int)x0f, 0), W - 1);
      int x1i = min(x0 + 1, W - 1);
      ushort4 v00 = *(const ushort4*)(f + ((size_t)y0 * W + x0) * 256 + c0);
      ushort4 v01 = *(const ushort4*)(f + ((size_t)y0 * W + x1i) * 256 + c0);
      ushort4 v10 = *(const ushort4*)(f + ((size_t)y1i * W + x0) * 256 + c0);
      ushort4 v11 = *(const ushort4*)(f + ((size_t)y1i * W + x1i) * 256 + c0);
      ushort4 o;
      {
        float a = bf2f(v00.x), bq = bf2f(v01.x), cq = bf2f(v10.x), d = bf2f(v11.x);
        float top = a + lx * (bq - a), bot = cq + lx * (d - cq);
        o.x = f2bf(top + ly * (bot - top));
      }
      {
        float a = bf2f(v00.y), bq = bf2f(v01.y), cq = bf2f(v10.y), d = bf2f(v11.y);
        float top = a + lx * (bq - a), bot = cq + lx * (d - cq);
        o.y = f2bf(top + ly * (bot - top));
      }
      {
        float a = bf2f(v00.z), bq = bf2f(v01.z), cq = bf2f(v10.z), d = bf2f(v11.z);
        float top = a + lx * (bq - a), bot = cq + lx * (d - cq);
        o.z = f2bf(top + ly * (bot - top));
      }
      {
        float a = bf2f(v00.w), bq = bf2f(v01.w), cq = bf2f(v10.w), d = bf2f(v11.w);
        float top = a + lx * (bq - a), bot = cq + lx * (d - cq);
        o.w = f2bf(top + ly * (bot - top));
      }
      *(ushort4*)(out + p * 256 + c0) = o;
    }
  } else if (b < 4096) {
    // repack_w1 half-row: [o][c][hw] -> [o][hw*256 + h*128 + cc], cc in [0,128)
    int idx = b - 2048;
    int o = idx >> 1, h = idx & 1;
    const float4* src = (const float4*)(c1w + (size_t)o * KP + h * 6272);
    for (int k = t; k < 1568; k += 256) {   // 1568 float4 = 6272 floats
      float4 v = src[k];
      ushort4 q;
      q.x = f2bf(v.x); q.y = f2bf(v.y); q.z = f2bf(v.z); q.w = f2bf(v.w);
      *(ushort4*)&srep[k * 4] = q;          // srep[cc*49+hw]
    }
    __syncthreads();
    unsigned short* dst = w1p + (size_t)o * KP + h * 128;
    int ch4 = (t & 31) * 4;   // 0..124
    int jw = t >> 5;          // 0..7
    for (int j = jw; j < 49; j += 8) {
      ushort4 q;
      q.x = srep[(ch4 + 0) * 49 + j];
      q.y = srep[(ch4 + 1) * 49 + j];
      q.z = srep[(ch4 + 2) * 49 + j];
      q.w = srep[(ch4 + 3) * 49 + j];
      *(ushort4*)(dst + j * 256 + ch4) = q;
    }
  } else if (b < 5120) {
    int j4 = (b - 4096) * 256 + t;   // float4 index into conv2_w
    float4 v = ((const float4*)c2w)[j4];
    ushort4 q;
    q.x = f2bf(v.x); q.y = f2bf(v.y); q.z = f2bf(v.z); q.w = f2bf(v.w);
    *(ushort4*)(w2b + (size_t)j4 * 4) = q;
  } else if (b < 5568) {
    int row = b - 5120;
    int k = t * 4;  // 256 threads x 4 = 1024
    float4 v = {0.f, 0.f, 0.f, 0.f};
    if (row < NCLS)      v = *(const float4*)(lw + (size_t)row * 1024 + k);
    else if (row < N3)   v = *(const float4*)(bw + (size_t)(row - NCLS) * 1024 + k);
    ushort4 q;
    q.x = f2bf(v.x); q.y = f2bf(v.y); q.z = f2bf(v.z); q.w = f2bf(v.w);
    *(ushort4*)(w3b + (size_t)row * 1024 + k) = q;
  } else {
    for (int i = t; i < 1024; i += 256) {
      float sc = g1[i] * rsqrtf(v1[i] + BN_EPS);
      s1[i] = sc;
      t1[i] = (c1b[i] - m1[i]) * sc + b1[i];
      float ss = g2[i] * rsqrtf(v2[i] + BN_EPS);
      s2[i] = ss;
      t2[i] = (c2b[i] - m2[i]) * ss + b2[i];
    }
    for (int i = t; i < N3P; i += 256)
      b3[i] = (i < NCLS) ? lb[i] : (i < N3 ? bb[i - NCLS] : 0.0f);
  }
}

// =================== GEMM1 split-K v2: 256x256 tile, 8 waves, BK=64 ========
// Counted-vmcnt 2-phase-per-K-tile pipeline (T3+T4+T5), double-buffered LDS
// (128 KiB), K-phase-split staging so the main loop never drains vmcnt to 0.
__global__ __launch_bounds__(512, 2) void gemm1_sk2(
    const unsigned short* __restrict__ A, const unsigned short* __restrict__ B,
    unsigned short* __restrict__ part) {
  __shared__ unsigned short AsF[4 * 8192];  // [slot][kk][256*32] = 64 KiB
  __shared__ unsigned short BsF[4 * 8192];  // 64 KiB
  int bid = blockIdx.x;
  int kz = bid & 7;          // XCD k owns K-slice k (grid=256 -> 1 block/CU)
  int u = bid >> 3;          // 0..31 tiles
  int bn0 = (u & 3) * 256;
  int bm0 = (u >> 2) * 256;
  int koff, klen;
  kslice(kz, koff, klen);
  int nt = klen >> 6;        // 24 or 25 K-tiles

  int t = threadIdx.x;
  int lane = t & 63, w = t >> 6;   // 8 waves
  int wr = w >> 2, wc = w & 3;     // 2 x 4 wave grid; per-wave C = 128x64
  int ln = lane & 15, q = lane >> 4;

  int clog = (lane & 3) ^ ((lane >> 3) & 3);
  int l4 = lane >> 2;
  const unsigned short* gA0 = A + (size_t)(bm0 + w * 32 + l4) * KP + koff + clog * 8;
  const unsigned short* gA1 = gA0 + (size_t)16 * KP;
  const unsigned short* gB0 = B + (size_t)(bn0 + w * 32 + l4) * KP + koff + clog * 8;
  const unsigned short* gB1 = gB0 + (size_t)16 * KP;
  int dc0 = (w * 128 + lane) * 8;       // LDS dest (shorts), lane-affine x16B
  int dc1 = dc0 + 64 * 8;

  int rxor = (q ^ ((ln >> 1) & 3)) * 8;
  int rdA = (wr * 128 + ln) * 32 + rxor;
  int rdB = (wc * 64 + ln) * 32 + rxor;

  f32x4 acc[8][4] = {};

  // ---- prologue: stage tile 0, kk=0 then kk=1 (8 loads) ----
#pragma unroll
  for (int kk = 0; kk < 2; ++kk) {
    int src = kk * 32;
    int db = kk * 8192;
    gld16(gA0 + src, AsF + db + dc0);
    gld16(gA1 + src, AsF + db + dc1);
    gld16(gB0 + src, BsF + db + dc0);
    gld16(gB1 + src, BsF + db + dc1);
  }
  asm volatile("s_waitcnt vmcnt(4)" ::: "memory");  // tile0 kk0 retired
  __builtin_amdgcn_s_barrier();
  asm volatile("" ::: "memory");

  for (int tt = 0; tt < nt; ++tt) {
    int slot = tt & 1;
    int nslot = slot ^ 1;
    int knext = (tt + 1 < nt) ? (tt + 1) * 64 : 0;
#pragma unroll
    for (int kk = 0; kk < 2; ++kk) {
      int rb = (slot * 2 + kk) * 8192;
      bf16x8 af[8], bfr[4];
#pragma unroll
      for (int mi = 0; mi < 8; ++mi)
        af[mi] = *(const bf16x8*)&AsF[rb + rdA + mi * 512];
#pragma unroll
      for (int nj = 0; nj < 4; ++nj)
        bfr[nj] = *(const bf16x8*)&BsF[rb + rdB + nj * 512];

      int src = knext + kk * 32;
      int db = (nslot * 2 + kk) * 8192;
      gld16(gA0 + src, AsF + db + dc0);
      gld16(gA1 + src, AsF + db + dc1);
      gld16(gB0 + src, BsF + db + dc0);
      gld16(gB1 + src, BsF + db + dc1);

      asm volatile("s_waitcnt vmcnt(4)" ::: "memory");
      __builtin_amdgcn_s_barrier();
      asm volatile("" ::: "memory");

      __builtin_amdgcn_s_setprio(1);
#pragma unroll
      for (int mi = 0; mi < 8; ++mi)
#pragma unroll
        for (int nj = 0; nj < 4; ++nj)
          acc[mi][nj] = __builtin_amdgcn_mfma_f32_16x16x32_bf16(
              af[mi], bfr[nj], acc[mi][nj], 0, 0, 0);
      __builtin_amdgcn_s_setprio(0);

      asm volatile("" ::: "memory");
      __builtin_amdgcn_s_barrier();
      asm volatile("" ::: "memory");
    }
  }

  unsigned short* po = part + (size_t)kz * MPAD * N1;
#pragma unroll
  for (int mi = 0; mi < 8; ++mi) {
    int m = bm0 + wr * 128 + mi * 16 + q * 4;
#pragma unroll
    for (int nj = 0; nj < 4; ++nj) {
      int n = bn0 + wc * 64 + nj * 16 + ln;
#pragma unroll
      for (int r = 0; r < 4; ++r)
        po[(size_t)(m + r) * N1 + n] = f2bf(acc[mi][nj][r]);
    }
  }
}

// =================== split-K reduce (bf16 partials) + BN1 + ReLU ===========
__global__ void reduce_sk(const unsigned short* __restrict__ part,
                          const float* __restrict__ sc, const float* __restrict__ sh,
                          unsigned short* __restrict__ outb) {
  const size_t P = (size_t)MPAD * N1;
  int m = blockIdx.x;
  int t = threadIdx.x;
  float4 v = {0.f, 0.f, 0.f, 0.f};
#pragma unroll
  for (int kz = 0; kz < KSPLIT; ++kz) {
    ushort4 u = *(const ushort4*)(part + kz * P + (size_t)m * N1 + t * 4);
    v.x += bf2f(u.x); v.y += bf2f(u.y); v.z += bf2f(u.z); v.w += bf2f(u.w);
  }
  int n0 = t * 4;
  ushort4 o;
  if (m < NROI) {
    o.x = f2bf(fmaxf(v.x * sc[n0 + 0] + sh[n0 + 0], 0.0f));
    o.y = f2bf(fmaxf(v.y * sc[n0 + 1] + sh[n0 + 1], 0.0f));
    o.z = f2bf(fmaxf(v.z * sc[n0 + 2] + sh[n0 + 2], 0.0f));
    o.w = f2bf(fmaxf(v.w * sc[n0 + 3] + sh[n0 + 3], 0.0f));
  } else {
    o = make_ushort4(0, 0, 0, 0);
  }
  *(ushort4*)(outb + (size_t)m * N1 + n0) = o;
}

// =================== bf16 MFMA GEMM (64x64 tile, BK=64, swizzled) ==========
template <int MODE>
__global__ __launch_bounds__(256) void gemm_bt(
    const unsigned short* __restrict__ A, const unsigned short* __restrict__ B,
    int M, int N, int K,
    const float* __restrict__ sc, const float* __restrict__ sh,
    unsigned short* __restrict__ outb, float* __restrict__ outf,
    int validM, int ldo) {
  __shared__ unsigned short As[64 * 64];  // 8 KB
  __shared__ unsigned short Bs[64 * 64];
  int bm0 = blockIdx.y * 64;
  int bn0 = blockIdx.x * 64;
  int t = threadIdx.x;
  int lane = t & 63, w = t >> 6;
  int wm = (w & 1) * 32, wn = (w >> 1) * 32;
  int ln = lane & 15, q = lane >> 4;

  int r8 = t >> 3, j8 = t & 7;
  int sj = j8 ^ (r8 & 7);
  const unsigned short* ga = A + (size_t)(bm0 + r8) * K + sj * 8;
  const unsigned short* gb = B + (size_t)(bn0 + r8) * K + sj * 8;
  unsigned short* la = &As[t * 8];
  unsigned short* lb = &Bs[t * 8];
  int e = ln & 7;

  f32x4 acc00 = {0.f, 0.f, 0.f, 0.f}, acc01 = {0.f, 0.f, 0.f, 0.f};
  f32x4 acc10 = {0.f, 0.f, 0.f, 0.f}, acc11 = {0.f, 0.f, 0.f, 0.f};

  for (int k0 = 0; k0 < K; k0 += 64) {
    gld16(ga + k0, la);
    gld16(ga + k0 + (size_t)32 * K, la + 2048);
    gld16(gb + k0, lb);
    gld16(gb + k0 + (size_t)32 * K, lb + 2048);
    __syncthreads();
#pragma unroll
    for (int h = 0; h < 2; ++h) {
      int slot = ((h * 4 + q) ^ e) * 8;
      bf16x8 a0 = *(const bf16x8*)&As[(wm + ln) * 64 + slot];
      bf16x8 a1 = *(const bf16x8*)&As[(wm + 16 + ln) * 64 + slot];
      bf16x8 b0 = *(const bf16x8*)&Bs[(wn + ln) * 64 + slot];
      bf16x8 b1 = *(const bf16x8*)&Bs[(wn + 16 + ln) * 64 + slot];
      acc00 = __builtin_amdgcn_mfma_f32_16x16x32_bf16(a0, b0, acc00, 0, 0, 0);
      acc01 = __builtin_amdgcn_mfma_f32_16x16x32_bf16(a0, b1, acc01, 0, 0, 0);
      acc10 = __builtin_amdgcn_mfma_f32_16x16x32_bf16(a1, b0, acc10, 0, 0, 0);
      acc11 = __builtin_amdgcn_mfma_f32_16x16x32_bf16(a1, b1, acc11, 0, 0, 0);
    }
    __syncthreads();
  }

  f32x4 accs[2][2] = {{acc00, acc01}, {acc10, acc11}};
#pragma unroll
  for (int i = 0; i < 2; ++i)
#pragma unroll
    for (int j = 0; j < 2; ++j)
#pragma unroll
      for (int r = 0; r < 4; ++r) {
        int m = bm0 + wm + i * 16 + q * 4 + r;
        int n = bn0 + wn + j * 16 + ln;
        float v = accs[i][j][r];
        if (MODE == 1) {
          float o = fmaxf(v * sc[n] + sh[n], 0.0f);
          outb[(size_t)m * ldo + n] = (m < validM) ? f2bf(o) : (unsigned short)0;
        } else {
          outf[(size_t)m * ldo + n] = v + sh[n];
        }
      }
}

// =================== softmax + output scatter ===============================
__global__ void head(const float* __restrict__ fc3, float* __restrict__ out) {
  int r = blockIdx.x;
  int t = threadIdx.x;  // 0..63
  const float* row = fc3 + (size_t)r * N3P;
  float v0 = (t < NCLS) ? row[t] : -INFINITY;
  float v1 = (t + 64 < NCLS) ? row[t + 64] : -INFINITY;
  float m = fmaxf(v0, v1);
#pragma unroll
  for (int o = 32; o > 0; o >>= 1) m = fmaxf(m, __shfl_xor(m, o, 64));
  float e0 = (t < NCLS) ? expf(v0 - m) : 0.0f;
  float e1 = (t + 64 < NCLS) ? expf(v1 - m) : 0.0f;
  float s = e0 + e1;
#pragma unroll
  for (int o = 32; o > 0; o >>= 1) s += __shfl_xor(s, o, 64);
  float invs = 1.0f / s;
  float* ol = out + (size_t)r * NCLS;
  float* op = out + 162000 + (size_t)r * NCLS;
  float* ob = out + 324000 + (size_t)r * NBOX;
  if (t < NCLS) { ol[t] = v0; op[t] = e0 * invs; }
  if (t + 64 < NCLS) { ol[t + 64] = v1; op[t + 64] = e1 * invs; }
  for (int j = t; j < NBOX; j += 64) ob[j] = row[NCLS + j];
}

extern "C" void kernel_launch(void* const* d_in, const int* in_sizes, int n_in,
                              void* d_out, int out_size, void* d_ws, size_t ws_size,
                              hipStream_t stream) {
  const float* p2  = (const float*)d_in[0];
  const float* p3  = (const float*)d_in[1];
  const float* p4  = (const float*)d_in[2];
  const float* p5  = (const float*)d_in[3];
  const float* roi = (const float*)d_in[4];
  const float* c1w = (const float*)d_in[5];
  const float* c1b = (const float*)d_in[6];
  const float* g1  = (const float*)d_in[7];
  const float* b1  = (const float*)d_in[8];
  const float* m1  = (const float*)d_in[9];
  const float* v1  = (const float*)d_in[10];
  const float* c2w = (const float*)d_in[11];
  const float* c2b = (const float*)d_in[12];
  const float* g2  = (const float*)d_in[13];
  const float* b2  = (const float*)d_in[14];
  const float* m2  = (const float*)d_in[15];
  const float* v2  = (const float*)d_in[16];
  const float* lw  = (const float*)d_in[17];
  const float* lb  = (const float*)d_in[18];
  const float* bw  = (const float*)d_in[19];
  const float* bb  = (const float*)d_in[20];
  float* out = (float*)d_out;

  char* ws = (char*)d_ws;
  size_t off = 0;
  auto alloc = [&](size_t bytes) {
    void* p = ws + off;
    off = (off + bytes + 255) & ~(size_t)255;
    return p;
  };
  unsigned short* pooled = (unsigned short*)alloc((size_t)MPAD * KP * 2);
  unsigned short* w1p    = (unsigned short*)alloc((size_t)N1 * KP * 2);
  unsigned short* w2b    = (unsigned short*)alloc((size_t)N1 * N1 * 2);
  unsigned short* w3b    = (unsigned short*)alloc((size_t)N3P * N1 * 2);
  unsigned short* a2     = (unsigned short*)alloc((size_t)MPAD * N1 * 2);
  unsigned short* shd    = (unsigned short*)alloc((size_t)MPAD * N1 * 2);
  float* fc3 = (float*)alloc((size_t)MPAD * N3P * 4);
  // union region: transposed maps (44.6 MB) live only until roi_prep;
  // bf16 split-K partials (32 MB) written after — alias them.
  char* ub = (char*)alloc((size_t)48 * 1024 * 1024);
  unsigned short* f2t = (unsigned short*)ub;
  unsigned short* f3t = (unsigned short*)(ub + 33554432);
  unsigned short* f4t = (unsigned short*)(ub + 33554432 + 8388608);
  unsigned short* f5t = (unsigned short*)(ub + 33554432 + 8388608 + 2097152);
  unsigned short* part = (unsigned short*)ub;
  float* s1  = (float*)alloc(1024 * 4);
  float* t1  = (float*)alloc(1024 * 4);
  float* s2  = (float*)alloc(1024 * 4);
  float* t2  = (float*)alloc(1024 * 4);
  float* b3  = (float*)alloc(N3P * 4);

  // transpose only — weight prep moved into roi_prep's grid (overlaps the
  // latency-bound gather; stream order still places it before gemm1).
  front_t<<<1360, 256, 0, stream>>>(p2, p3, p4, p5, f2t, f3t, f4t, f5t);

  roi_prep<<<5569, 256, 0, stream>>>(f2t, f3t, f4t, f5t, roi, pooled,
                                     c1w, c2w, lw, bw,
                                     c1b, g1, b1, m1, v1, c2b, g2, b2, m2, v2,
                                     lb, bb,
                                     w1p, w2b, w3b, s1, t1, s2, t2, b3);

  // GEMM1: [2048 x 12544] x [1024 x 12544]^T split-K=8, 256^2 tiles,
  // counted-vmcnt pipeline; grid = 256 = exactly 1 block/CU.
  gemm1_sk2<<<256, 512, 0, stream>>>(pooled, w1p, part);
  reduce_sk<<<MPAD, 256, 0, stream>>>(part, s1, t1, a2);

  // GEMM2: [2048 x 1024] x [1024 x 1024]^T -> BN2+ReLU -> shd (bf16)
  gemm_bt<1><<<dim3(N1 / 64, MPAD / 64), 256, 0, stream>>>(
      a2, w2b, MPAD, N1, N1, s2, t2, shd, nullptr, NROI, N1);
  // GEMM3: [2048 x 1024] x [448 x 1024]^T + bias -> fc3 (f32)
  gemm_bt<2><<<dim3(N3P / 64, MPAD / 64), 256, 0, stream>>>(
      shd, w3b, MPAD, N3P, N1, nullptr, b3, nullptr, fc3, NROI, N3P);

  head<<<NROI, 64, 0, stream>>>(fc3, out);
}

// Round 4
// 309.684 us; speedup vs baseline: 1.0183x; 1.0183x over previous
//
#include <hip/hip_runtime.h>
#include <stdint.h>

#define NROI 2000
#define MPAD 2048
#define KP   12544   // 256*49
#define N1   1024
#define NCLS 81
#define NBOX 324
#define N3   405
#define N3P  448
#define BN_EPS 0.001f
#define KSPLIT 8

typedef __attribute__((ext_vector_type(8))) short bf16x8;
typedef __attribute__((ext_vector_type(4))) float f32x4;
typedef __attribute__((ext_vector_type(8))) unsigned short u16x8;

__device__ inline unsigned short f2bf(float f) {
  union { float f; unsigned u; } v; v.f = f;
  unsigned r = v.u + 0x7fffu + ((v.u >> 16) & 1u);
  return (unsigned short)(r >> 16);
}

__device__ inline float bf2f(unsigned short h) {
  union { unsigned u; float f; } v; v.u = (unsigned)h << 16; return v.f;
}

__device__ inline void gld16(const unsigned short* g, unsigned short* l) {
  __builtin_amdgcn_global_load_lds(
      (const __attribute__((address_space(1))) void*)g,
      (__attribute__((address_space(3))) void*)l, 16, 0, 0);
}

// K-slice table: 4 slices of 1536 + 4 of 1600 (all BK=64, no tail)
__device__ __forceinline__ void kslice(int kz, int& off, int& len) {
  if (kz < 4) { off = kz * 1536; len = 1536; }
  else        { off = 6144 + (kz - 4) * 1600; len = 1600; }
}

// =================== front_t: fmap transpose only ==========================
// [256][HW] f32 -> [HW][256] bf16, in-register, no LDS. 1360 blocks.
__global__ __launch_bounds__(256) void front_t(
    const float* __restrict__ p2, const float* __restrict__ p3,
    const float* __restrict__ p4, const float* __restrict__ p5,
    unsigned short* __restrict__ f2t, unsigned short* __restrict__ f3t,
    unsigned short* __restrict__ f4t, unsigned short* __restrict__ f5t) {
  int bb2 = blockIdx.x;
  int t = threadIdx.x;
  const float* src;
  unsigned short* dst;
  int HW;
  if (bb2 < 1024)      { src = p2; dst = f2t; HW = 65536; }
  else if (bb2 < 1280) { bb2 -= 1024; src = p3; dst = f3t; HW = 16384; }
  else if (bb2 < 1344) { bb2 -= 1280; src = p4; dst = f4t; HW = 4096; }
  else                 { bb2 -= 1344; src = p5; dst = f5t; HW = 1024; }
  int p0 = bb2 * 64;
  int lane = t & 63, w = t >> 6;
  int pq = (lane & 15) * 4;       // pixel quad within tile
  int cg = (lane >> 4) * 8;       // channel sub-block
#pragma unroll
  for (int it = 0; it < 2; ++it) {
    int c = w * 64 + it * 32 + cg;
    const float* sp = src + (size_t)c * HW + p0 + pq;
    float4 v[8];
#pragma unroll
    for (int k = 0; k < 8; ++k)
      v[k] = *(const float4*)(sp + (size_t)k * HW);
    unsigned short* dp = dst + (size_t)(p0 + pq) * 256 + c;
    u16x8 o0, o1, o2, o3;
#pragma unroll
    for (int k = 0; k < 8; ++k) {
      o0[k] = f2bf(v[k].x);
      o1[k] = f2bf(v[k].y);
      o2[k] = f2bf(v[k].z);
      o3[k] = f2bf(v[k].w);
    }
    *(u16x8*)(dp)       = o0;
    *(u16x8*)(dp + 256) = o1;
    *(u16x8*)(dp + 512) = o2;
    *(u16x8*)(dp + 768) = o3;
  }
}

// =================== roi_prep: ROI Align + weight prep (merged grid) =======
// blocks [0,2048): ROI Align gather from [HW][256] bf16 maps
// blocks [2048,4096): repack conv1_w half-rows -> w1p [o][hw*256+c] bf16
// blocks [4096,5120): cvt conv2_w -> bf16 (float4)
// blocks [5120,5568): pack logits_w+bbox_w -> w3b
// block 5568: BN folding + bias concat
__global__ __launch_bounds__(256) void roi_prep(
    const unsigned short* __restrict__ f2t, const unsigned short* __restrict__ f3t,
    const unsigned short* __restrict__ f4t, const unsigned short* __restrict__ f5t,
    const float* __restrict__ rois, unsigned short* __restrict__ pooled,
    const float* __restrict__ c1w, const float* __restrict__ c2w,
    const float* __restrict__ lw, const float* __restrict__ bw,
    const float* c1b, const float* g1, const float* b1, const float* m1, const float* v1,
    const float* c2b, const float* g2, const float* b2, const float* m2, const float* v2,
    const float* lb, const float* bb,
    unsigned short* __restrict__ w1p, unsigned short* __restrict__ w2b,
    unsigned short* __restrict__ w3b,
    float* s1, float* t1, float* s2, float* t2, float* b3) {
  __shared__ unsigned short srep[6272];  // 12544 B, repack branch only
  int b = blockIdx.x;
  int t = threadIdx.x;
  if (b < 2048) {
    int n = b;
    int lane = t & 63, w = t >> 6;
    int c0 = lane * 4;
    unsigned short* out = pooled + (size_t)n * KP;
    if (n >= NROI) {
      for (int p = w; p < 49; p += 4)
        *(ushort4*)(out + p * 256 + c0) = make_ushort4(0, 0, 0, 0);
      return;
    }
    float x1 = rois[n * 4 + 0], y1 = rois[n * 4 + 1];
    float x2 = rois[n * 4 + 2], y2 = rois[n * 4 + 3];
    float area = (y2 - y1) * (x2 - x1);
    float lvl_f = rintf(log2f(sqrtf(area) / 224.0f)) + 4.0f;
    lvl_f = fminf(fmaxf(lvl_f, 2.0f), 5.0f);
    int lvl = (int)lvl_f;
    const unsigned short* f;
    int H;
    if (lvl == 2)      { f = f2t; H = 256; }
    else if (lvl == 3) { f = f3t; H = 128; }
    else if (lvl == 4) { f = f4t; H = 64;  }
    else               { f = f5t; H = 32;  }
    int W = H;
    const float inv = 1.0f / 1024.0f;
    float yn1 = y1 * inv, xn1 = x1 * inv, yn2 = y2 * inv, xn2 = x2 * inv;
    float hs = (yn2 - yn1) * (H - 1);
    float ws = (xn2 - xn1) * (W - 1);
    float yb = yn1 * (H - 1);
    float xb = xn1 * (W - 1);

    for (int p = w; p < 49; p += 4) {
      int py = p / 7, px = p - py * 7;
      float ysv = yb + ((float)py / 6.0f) * hs;
      float xsv = xb + ((float)px / 6.0f) * ws;
      float y0f = floorf(ysv), x0f = floorf(xsv);
      float ly = ysv - y0f, lx = xsv - x0f;
      int y0 = min(max((int)y0f, 0), H - 1);
      int y1i = min(y0 + 1, H - 1);
      int x0 = min(max((int)x0f, 0), W - 1);
      int x1i = min(x0 + 1, W - 1);
      ushort4 v00 = *(const ushort4*)(f + ((size_t)y0 * W + x0) * 256 + c0);
      ushort4 v01 = *(const ushort4*)(f + ((size_t)y0 * W + x1i) * 256 + c0);
      ushort4 v10 = *(const ushort4*)(f + ((size_t)y1i * W + x0) * 256 + c0);
      ushort4 v11 = *(const ushort4*)(f + ((size_t)y1i * W + x1i) * 256 + c0);
      ushort4 o;
      {
        float a = bf2f(v00.x), bq = bf2f(v01.x), cq = bf2f(v10.x), d = bf2f(v11.x);
        float top = a + lx * (bq - a), bot = cq + lx * (d - cq);
        o.x = f2bf(top + ly * (bot - top));
      }
      {
        float a = bf2f(v00.y), bq = bf2f(v01.y), cq = bf2f(v10.y), d = bf2f(v11.y);
        float top = a + lx * (bq - a), bot = cq + lx * (d - cq);
        o.y = f2bf(top + ly * (bot - top));
      }
      {
        float a = bf2f(v00.z), bq = bf2f(v01.z), cq = bf2f(v10.z), d = bf2f(v11.z);
        float top = a + lx * (bq - a), bot = cq + lx * (d - cq);
        o.z = f2bf(top + ly * (bot - top));
      }
      {
        float a = bf2f(v00.w), bq = bf2f(v01.w), cq = bf2f(v10.w), d = bf2f(v11.w);
        float top = a + lx * (bq - a), bot = cq + lx * (d - cq);
        o.w = f2bf(top + ly * (bot - top));
      }
      *(ushort4*)(out + p * 256 + c0) = o;
    }
  } else if (b < 4096) {
    // repack_w1 half-row: [o][c][hw] -> [o][hw*256 + h*128 + cc], cc in [0,128)
    int idx = b - 2048;
    int o = idx >> 1, h = idx & 1;
    const float4* src = (const float4*)(c1w + (size_t)o * KP + h * 6272);
    for (int k = t; k < 1568; k += 256) {   // 1568 float4 = 6272 floats
      float4 v = src[k];
      ushort4 q;
      q.x = f2bf(v.x); q.y = f2bf(v.y); q.z = f2bf(v.z); q.w = f2bf(v.w);
      *(ushort4*)&srep[k * 4] = q;          // srep[cc*49+hw]
    }
    __syncthreads();
    unsigned short* dst = w1p + (size_t)o * KP + h * 128;
    int ch4 = (t & 31) * 4;   // 0..124
    int jw = t >> 5;          // 0..7
    for (int j = jw; j < 49; j += 8) {
      ushort4 q;
      q.x = srep[(ch4 + 0) * 49 + j];
      q.y = srep[(ch4 + 1) * 49 + j];
      q.z = srep[(ch4 + 2) * 49 + j];
      q.w = srep[(ch4 + 3) * 49 + j];
      *(ushort4*)(dst + j * 256 + ch4) = q;
    }
  } else if (b < 5120) {
    int j4 = (b - 4096) * 256 + t;   // float4 index into conv2_w
    float4 v = ((const float4*)c2w)[j4];
    ushort4 q;
    q.x = f2bf(v.x); q.y = f2bf(v.y); q.z = f2bf(v.z); q.w = f2bf(v.w);
    *(ushort4*)(w2b + (size_t)j4 * 4) = q;
  } else if (b < 5568) {
    int row = b - 5120;
    int k = t * 4;  // 256 threads x 4 = 1024
    float4 v = {0.f, 0.f, 0.f, 0.f};
    if (row < NCLS)      v = *(const float4*)(lw + (size_t)row * 1024 + k);
    else if (row < N3)   v = *(const float4*)(bw + (size_t)(row - NCLS) * 1024 + k);
    ushort4 q;
    q.x = f2bf(v.x); q.y = f2bf(v.y); q.z = f2bf(v.z); q.w = f2bf(v.w);
    *(ushort4*)(w3b + (size_t)row * 1024 + k) = q;
  } else {
    for (int i = t; i < 1024; i += 256) {
      float sc = g1[i] * rsqrtf(v1[i] + BN_EPS);
      s1[i] = sc;
      t1[i] = (c1b[i] - m1[i]) * sc + b1[i];
      float ss = g2[i] * rsqrtf(v2[i] + BN_EPS);
      s2[i] = ss;
      t2[i] = (c2b[i] - m2[i]) * ss + b2[i];
    }
    for (int i = t; i < N3P; i += 256)
      b3[i] = (i < NCLS) ? lb[i] : (i < N3 ? bb[i - NCLS] : 0.0f);
  }
}

// =================== GEMM1 split-K v3: 256x256 tile, ring-4 pipeline =======
// Phases of K=32. Ring of 4 phase-buffers (same 128 KiB LDS as v2).
// 3-phase DMA lookahead: issue buf[ph+3], wait vmcnt(8) (retires ph+1),
// ONE barrier per phase. MFMA precedes the vmcnt wait so matrix work
// overlaps DMA completion. Hazard ledger in session notes: RAW (slot ph
// loads retired by all waves' vmcnt(8)@ph-1 + barrier), WAR (slot ph+3
// last read @ph-1, all readers done before B(ph-1)), disjoint slots for
// concurrent read/DMA. Phase order identical to v2 -> bit-identical acc.
__global__ __launch_bounds__(512, 2) void gemm1_sk3(
    const unsigned short* __restrict__ A, const unsigned short* __restrict__ B,
    unsigned short* __restrict__ part) {
  __shared__ unsigned short AsF[4 * 8192];  // ring of 4 x [256][32] = 64 KiB
  __shared__ unsigned short BsF[4 * 8192];  // 64 KiB
  int bid = blockIdx.x;
  int kz = bid & 7;          // XCD k owns K-slice k (grid=256 -> 1 block/CU)
  int u = bid >> 3;          // 0..31 tiles
  int bn0 = (u & 3) * 256;
  int bm0 = (u >> 2) * 256;
  int koff, klen;
  kslice(kz, koff, klen);
  int nph = klen >> 5;       // 48 or 50 phases of K=32

  int t = threadIdx.x;
  int lane = t & 63, w = t >> 6;   // 8 waves
  int wr = w >> 2, wc = w & 3;     // 2 x 4 wave grid; per-wave C = 128x64
  int ln = lane & 15, q = lane >> 4;

  int clog = (lane & 3) ^ ((lane >> 3) & 3);
  int l4 = lane >> 2;
  const unsigned short* gA0 = A + (size_t)(bm0 + w * 32 + l4) * KP + koff + clog * 8;
  const unsigned short* gA1 = gA0 + (size_t)16 * KP;
  const unsigned short* gB0 = B + (size_t)(bn0 + w * 32 + l4) * KP + koff + clog * 8;
  const unsigned short* gB1 = gB0 + (size_t)16 * KP;
  int dc0 = (w * 128 + lane) * 8;       // LDS dest (shorts), lane-affine x16B
  int dc1 = dc0 + 64 * 8;

  int rxor = (q ^ ((ln >> 1) & 3)) * 8;
  int rdA = (wr * 128 + ln) * 32 + rxor;
  int rdB = (wc * 64 + ln) * 32 + rxor;

  f32x4 acc[8][4] = {};

  // ---- prologue: issue phases 0..2 (12 loads/wave) ----
#pragma unroll
  for (int ph = 0; ph < 3; ++ph) {
    int src = ph * 32;
    int db = ph * 8192;
    gld16(gA0 + src, AsF + db + dc0);
    gld16(gA1 + src, AsF + db + dc1);
    gld16(gB0 + src, BsF + db + dc0);
    gld16(gB1 + src, BsF + db + dc1);
  }
  asm volatile("s_waitcnt vmcnt(8)" ::: "memory");  // phase-0 buffers retired
  __builtin_amdgcn_s_barrier();
  asm volatile("" ::: "memory");

  for (int ph = 0; ph < nph; ++ph) {
    int rb = (ph & 3) * 8192;
    bf16x8 af[8], bfr[4];
#pragma unroll
    for (int mi = 0; mi < 8; ++mi)
      af[mi] = *(const bf16x8*)&AsF[rb + rdA + mi * 512];
#pragma unroll
    for (int nj = 0; nj < 4; ++nj)
      bfr[nj] = *(const bf16x8*)&BsF[rb + rdB + nj * 512];

    // issue phase ph+3 into ring slot (ph+3)&3 (dummy reload past the end
    // keeps vmcnt arithmetic uniform; target slot is never read again)
    int phn = ph + 3;
    int src = (phn < nph) ? phn * 32 : 0;
    int db = (phn & 3) * 8192;
    gld16(gA0 + src, AsF + db + dc0);
    gld16(gA1 + src, AsF + db + dc1);
    gld16(gB0 + src, BsF + db + dc0);
    gld16(gB1 + src, BsF + db + dc1);

    __builtin_amdgcn_s_setprio(1);
#pragma unroll
    for (int mi = 0; mi < 8; ++mi)
#pragma unroll
      for (int nj = 0; nj < 4; ++nj)
        acc[mi][nj] = __builtin_amdgcn_mfma_f32_16x16x32_bf16(
            af[mi], bfr[nj], acc[mi][nj], 0, 0, 0);
    __builtin_amdgcn_s_setprio(0);

    // retire phase ph+1 (in-flight: ph+1,ph+2,ph+3 = 12 -> wait to 8)
    asm volatile("s_waitcnt vmcnt(8)" ::: "memory");
    __builtin_amdgcn_s_barrier();
    asm volatile("" ::: "memory");
  }

  // drain outstanding DMA before LDS goes out of scope / epilogue stores
  asm volatile("s_waitcnt vmcnt(0)" ::: "memory");

  unsigned short* po = part + (size_t)kz * MPAD * N1;
#pragma unroll
  for (int mi = 0; mi < 8; ++mi) {
    int m = bm0 + wr * 128 + mi * 16 + q * 4;
#pragma unroll
    for (int nj = 0; nj < 4; ++nj) {
      int n = bn0 + wc * 64 + nj * 16 + ln;
#pragma unroll
      for (int r = 0; r < 4; ++r)
        po[(size_t)(m + r) * N1 + n] = f2bf(acc[mi][nj][r]);
    }
  }
}

// =================== split-K reduce (bf16 partials) + BN1 + ReLU ===========
__global__ void reduce_sk(const unsigned short* __restrict__ part,
                          const float* __restrict__ sc, const float* __restrict__ sh,
                          unsigned short* __restrict__ outb) {
  const size_t P = (size_t)MPAD * N1;
  int m = blockIdx.x;
  int t = threadIdx.x;
  float4 v = {0.f, 0.f, 0.f, 0.f};
#pragma unroll
  for (int kz = 0; kz < KSPLIT; ++kz) {
    ushort4 u = *(const ushort4*)(part + kz * P + (size_t)m * N1 + t * 4);
    v.x += bf2f(u.x); v.y += bf2f(u.y); v.z += bf2f(u.z); v.w += bf2f(u.w);
  }
  int n0 = t * 4;
  ushort4 o;
  if (m < NROI) {
    o.x = f2bf(fmaxf(v.x * sc[n0 + 0] + sh[n0 + 0], 0.0f));
    o.y = f2bf(fmaxf(v.y * sc[n0 + 1] + sh[n0 + 1], 0.0f));
    o.z = f2bf(fmaxf(v.z * sc[n0 + 2] + sh[n0 + 2], 0.0f));
    o.w = f2bf(fmaxf(v.w * sc[n0 + 3] + sh[n0 + 3], 0.0f));
  } else {
    o = make_ushort4(0, 0, 0, 0);
  }
  *(ushort4*)(outb + (size_t)m * N1 + n0) = o;
}

// =================== bf16 MFMA GEMM (64x64 tile, BK=64, swizzled) ==========
template <int MODE>
__global__ __launch_bounds__(256) void gemm_bt(
    const unsigned short* __restrict__ A, const unsigned short* __restrict__ B,
    int M, int N, int K,
    const float* __restrict__ sc, const float* __restrict__ sh,
    unsigned short* __restrict__ outb, float* __restrict__ outf,
    int validM, int ldo) {
  __shared__ unsigned short As[64 * 64];  // 8 KB
  __shared__ unsigned short Bs[64 * 64];
  int bm0 = blockIdx.y * 64;
  int bn0 = blockIdx.x * 64;
  int t = threadIdx.x;
  int lane = t & 63, w = t >> 6;
  int wm = (w & 1) * 32, wn = (w >> 1) * 32;
  int ln = lane & 15, q = lane >> 4;

  int r8 = t >> 3, j8 = t & 7;
  int sj = j8 ^ (r8 & 7);
  const unsigned short* ga = A + (size_t)(bm0 + r8) * K + sj * 8;
  const unsigned short* gb = B + (size_t)(bn0 + r8) * K + sj * 8;
  unsigned short* la = &As[t * 8];
  unsigned short* lb = &Bs[t * 8];
  int e = ln & 7;

  f32x4 acc00 = {0.f, 0.f, 0.f, 0.f}, acc01 = {0.f, 0.f, 0.f, 0.f};
  f32x4 acc10 = {0.f, 0.f, 0.f, 0.f}, acc11 = {0.f, 0.f, 0.f, 0.f};

  for (int k0 = 0; k0 < K; k0 += 64) {
    gld16(ga + k0, la);
    gld16(ga + k0 + (size_t)32 * K, la + 2048);
    gld16(gb + k0, lb);
    gld16(gb + k0 + (size_t)32 * K, lb + 2048);
    __syncthreads();
#pragma unroll
    for (int h = 0; h < 2; ++h) {
      int slot = ((h * 4 + q) ^ e) * 8;
      bf16x8 a0 = *(const bf16x8*)&As[(wm + ln) * 64 + slot];
      bf16x8 a1 = *(const bf16x8*)&As[(wm + 16 + ln) * 64 + slot];
      bf16x8 b0 = *(const bf16x8*)&Bs[(wn + ln) * 64 + slot];
      bf16x8 b1 = *(const bf16x8*)&Bs[(wn + 16 + ln) * 64 + slot];
      acc00 = __builtin_amdgcn_mfma_f32_16x16x32_bf16(a0, b0, acc00, 0, 0, 0);
      acc01 = __builtin_amdgcn_mfma_f32_16x16x32_bf16(a0, b1, acc01, 0, 0, 0);
      acc10 = __builtin_amdgcn_mfma_f32_16x16x32_bf16(a1, b0, acc10, 0, 0, 0);
      acc11 = __builtin_amdgcn_mfma_f32_16x16x32_bf16(a1, b1, acc11, 0, 0, 0);
    }
    __syncthreads();
  }

  f32x4 accs[2][2] = {{acc00, acc01}, {acc10, acc11}};
#pragma unroll
  for (int i = 0; i < 2; ++i)
#pragma unroll
    for (int j = 0; j < 2; ++j)
#pragma unroll
      for (int r = 0; r < 4; ++r) {
        int m = bm0 + wm + i * 16 + q * 4 + r;
        int n = bn0 + wn + j * 16 + ln;
        float v = accs[i][j][r];
        if (MODE == 1) {
          float o = fmaxf(v * sc[n] + sh[n], 0.0f);
          outb[(size_t)m * ldo + n] = (m < validM) ? f2bf(o) : (unsigned short)0;
        } else {
          outf[(size_t)m * ldo + n] = v + sh[n];
        }
      }
}

// =================== softmax + output scatter ===============================
__global__ void head(const float* __restrict__ fc3, float* __restrict__ out) {
  int r = blockIdx.x;
  int t = threadIdx.x;  // 0..63
  const float* row = fc3 + (size_t)r * N3P;
  float v0 = (t < NCLS) ? row[t] : -INFINITY;
  float v1 = (t + 64 < NCLS) ? row[t + 64] : -INFINITY;
  float m = fmaxf(v0, v1);
#pragma unroll
  for (int o = 32; o > 0; o >>= 1) m = fmaxf(m, __shfl_xor(m, o, 64));
  float e0 = (t < NCLS) ? expf(v0 - m) : 0.0f;
  float e1 = (t + 64 < NCLS) ? expf(v1 - m) : 0.0f;
  float s = e0 + e1;
#pragma unroll
  for (int o = 32; o > 0; o >>= 1) s += __shfl_xor(s, o, 64);
  float invs = 1.0f / s;
  float* ol = out + (size_t)r * NCLS;
  float* op = out + 162000 + (size_t)r * NCLS;
  float* ob = out + 324000 + (size_t)r * NBOX;
  if (t < NCLS) { ol[t] = v0; op[t] = e0 * invs; }
  if (t + 64 < NCLS) { ol[t + 64] = v1; op[t + 64] = e1 * invs; }
  for (int j = t; j < NBOX; j += 64) ob[j] = row[NCLS + j];
}

extern "C" void kernel_launch(void* const* d_in, const int* in_sizes, int n_in,
                              void* d_out, int out_size, void* d_ws, size_t ws_size,
                              hipStream_t stream) {
  const float* p2  = (const float*)d_in[0];
  const float* p3  = (const float*)d_in[1];
  const float* p4  = (const float*)d_in[2];
  const float* p5  = (const float*)d_in[3];
  const float* roi = (const float*)d_in[4];
  const float* c1w = (const float*)d_in[5];
  const float* c1b = (const float*)d_in[6];
  const float* g1  = (const float*)d_in[7];
  const float* b1  = (const float*)d_in[8];
  const float* m1  = (const float*)d_in[9];
  const float* v1  = (const float*)d_in[10];
  const float* c2w = (const float*)d_in[11];
  const float* c2b = (const float*)d_in[12];
  const float* g2  = (const float*)d_in[13];
  const float* b2  = (const float*)d_in[14];
  const float* m2  = (const float*)d_in[15];
  const float* v2  = (const float*)d_in[16];
  const float* lw  = (const float*)d_in[17];
  const float* lb  = (const float*)d_in[18];
  const float* bw  = (const float*)d_in[19];
  const float* bb  = (const float*)d_in[20];
  float* out = (float*)d_out;

  char* ws = (char*)d_ws;
  size_t off = 0;
  auto alloc = [&](size_t bytes) {
    void* p = ws + off;
    off = (off + bytes + 255) & ~(size_t)255;
    return p;
  };
  unsigned short* pooled = (unsigned short*)alloc((size_t)MPAD * KP * 2);
  unsigned short* w1p    = (unsigned short*)alloc((size_t)N1 * KP * 2);
  unsigned short* w2b    = (unsigned short*)alloc((size_t)N1 * N1 * 2);
  unsigned short* w3b    = (unsigned short*)alloc((size_t)N3P * N1 * 2);
  unsigned short* a2     = (unsigned short*)alloc((size_t)MPAD * N1 * 2);
  unsigned short* shd    = (unsigned short*)alloc((size_t)MPAD * N1 * 2);
  float* fc3 = (float*)alloc((size_t)MPAD * N3P * 4);
  // union region: transposed maps (44.6 MB) live only until roi_prep;
  // bf16 split-K partials (32 MB) written after — alias them.
  char* ub = (char*)alloc((size_t)48 * 1024 * 1024);
  unsigned short* f2t = (unsigned short*)ub;
  unsigned short* f3t = (unsigned short*)(ub + 33554432);
  unsigned short* f4t = (unsigned short*)(ub + 33554432 + 8388608);
  unsigned short* f5t = (unsigned short*)(ub + 33554432 + 8388608 + 2097152);
  unsigned short* part = (unsigned short*)ub;
  float* s1  = (float*)alloc(1024 * 4);
  float* t1  = (float*)alloc(1024 * 4);
  float* s2  = (float*)alloc(1024 * 4);
  float* t2  = (float*)alloc(1024 * 4);
  float* b3  = (float*)alloc(N3P * 4);

  front_t<<<1360, 256, 0, stream>>>(p2, p3, p4, p5, f2t, f3t, f4t, f5t);

  roi_prep<<<5569, 256, 0, stream>>>(f2t, f3t, f4t, f5t, roi, pooled,
                                     c1w, c2w, lw, bw,
                                     c1b, g1, b1, m1, v1, c2b, g2, b2, m2, v2,
                                     lb, bb,
                                     w1p, w2b, w3b, s1, t1, s2, t2, b3);

  // GEMM1: [2048 x 12544] x [1024 x 12544]^T split-K=8, 256^2 tiles,
  // ring-4 counted-vmcnt pipeline; grid = 256 = exactly 1 block/CU.
  gemm1_sk3<<<256, 512, 0, stream>>>(pooled, w1p, part);
  reduce_sk<<<MPAD, 256, 0, stream>>>(part, s1, t1, a2);

  // GEMM2: [2048 x 1024] x [1024 x 1024]^T -> BN2+ReLU -> shd (bf16)
  gemm_bt<1><<<dim3(N1 / 64, MPAD / 64), 256, 0, stream>>>(
      a2, w2b, MPAD, N1, N1, s2, t2, shd, nullptr, NROI, N1);
  // GEMM3: [2048 x 1024] x [448 x 1024]^T + bias -> fc3 (f32)
  gemm_bt<2><<<dim3(N3P / 64, MPAD / 64), 256, 0, stream>>>(
      shd, w3b, MPAD, N3P, N1, nullptr, b3, nullptr, fc3, NROI, N3P);

  head<<<NROI, 64, 0, stream>>>(fc3, out);
}